// Round 18
// baseline (312.481 us; speedup 1.0000x reference)
//
#include <hip/hip_runtime.h>

#define N_NODES 50000
#define N_EDGES 800000
#define DIM 128
#define TOT_EDGES (N_EDGES + N_NODES)
#define LOG2E 1.44269504088896f

// bucketed CSR build
#define BSHIFT 9
#define BNODES 512
#define NB ((N_NODES + BNODES - 1) / BNODES)  // 98
#define BCAP 16384
#define EPB 4096
#define EPT 16
#define NBLK_A ((TOT_EDGES + EPB - 1) / EPB)  // 208
#define CONVX_BLOCKS ((N_NODES * (DIM / 2) + 255) / 256)  // 12500
#define CONVW_BLOCKS ((3 * 2 * DIM * DIM + 255) / 256)    // 384

typedef __attribute__((ext_vector_type(8))) _Float16 f16x8;
typedef __attribute__((ext_vector_type(2))) _Float16 h2;
typedef __attribute__((ext_vector_type(4))) float f32x4;
typedef decltype(__builtin_amdgcn_cvt_pkrtz(0.f, 0.f)) fp16v2;  // __fp16 x2

__device__ inline uint h2u(h2 v) { return __builtin_bit_cast(uint, v); }
__device__ inline h2 u2h(uint v) { return __builtin_bit_cast(h2, v); }
__device__ inline uint pk2u(fp16v2 v) { return __builtin_bit_cast(uint, v); }

// sum over each 16-lane group via DPP row rotations (pure VALU)
__device__ inline float rowsum16(float v) {
  int x;
  x = __builtin_amdgcn_update_dpp(0, __float_as_int(v), 0x128, 0xF, 0xF, true);  // row_ror:8
  v += __int_as_float(x);
  x = __builtin_amdgcn_update_dpp(0, __float_as_int(v), 0x124, 0xF, 0xF, true);  // row_ror:4
  v += __int_as_float(x);
  x = __builtin_amdgcn_update_dpp(0, __float_as_int(v), 0x122, 0xF, 0xF, true);  // row_ror:2
  v += __int_as_float(x);
  x = __builtin_amdgcn_update_dpp(0, __float_as_int(v), 0x121, 0xF, 0xF, true);  // row_ror:1
  v += __int_as_float(x);
  return v;
}

// sum over each 4-lane quad via quad_perm DPP (xor1 then xor2)
__device__ inline float quadsum4(float v) {
  int x;
  x = __builtin_amdgcn_update_dpp(0, __float_as_int(v), 0xB1, 0xF, 0xF, true);  // quad_perm [1,0,3,2]
  v += __int_as_float(x);
  x = __builtin_amdgcn_update_dpp(0, __float_as_int(v), 0x4E, 0xF, 0xF, true);  // quad_perm [2,3,0,1]
  v += __int_as_float(x);
  return v;
}

// ---------------- fused conversions (x->f16, W->Wt, attc, col pad, bcnt=0) ----

__global__ __launch_bounds__(256) void conv_kernel(const float* __restrict__ x,
                                                   uint* __restrict__ xb,
                                                   int* __restrict__ bcnt,
                                                   const float* __restrict__ Wl,
                                                   const float* __restrict__ Wr,
                                                   ushort* __restrict__ Wt,
                                                   const float* __restrict__ att,
                                                   uint* __restrict__ attc,
                                                   uint* __restrict__ col) {
  int b = blockIdx.x;
  if (b < CONVX_BLOCKS) {
    if (b == 0 && threadIdx.x < NB) bcnt[threadIdx.x] = 0;
    int t = b * 256 + threadIdx.x;
    if (t < N_NODES * (DIM / 2)) {
      float2 v = ((const float2*)x)[t];
      xb[t] = pk2u(__builtin_amdgcn_cvt_pkrtz(v.x, v.y));
    }
  } else {
    int bb = b - CONVX_BLOCKS;
    if (bb == 0) {
      int u = threadIdx.x;
      if (u < 192) {  // attc[l][64], log2e folded
        float a0 = att[2 * u] * LOG2E, a1 = att[2 * u + 1] * LOG2E;
        attc[u] = pk2u(__builtin_amdgcn_cvt_pkrtz(a0, a1));
      }
      if (u < 64) col[TOT_EDGES + u] = 0u;  // valid pad: clamp-free lookahead
    }
    int t = bb * 256 + threadIdx.x;
    if (t < 3 * 2 * DIM * DIM) {
      int k = t & 127;
      int n = (t >> 7) & 127;
      int w = (t >> 14) & 1;
      int l = t >> 15;
      const float* W = w ? Wr : Wl;
      _Float16 h = (_Float16)W[l * DIM * DIM + k * DIM + n];
      Wt[t] = __builtin_bit_cast(ushort, h);
    }
  }
}

// ---------------- CSR build: phase A — bucket partition ----------------
// bbuf entry packed in 4B: (src << 9) | (d & 511)

__global__ __launch_bounds__(256) void partA_kernel(const int* __restrict__ srcArr,
                                                    const int* __restrict__ dstArr,
                                                    int* __restrict__ bcnt,
                                                    uint* __restrict__ bbuf) {
  int tid = threadIdx.x;
  int e0 = blockIdx.x * EPB;
  __shared__ int hist[NB], base[NB], loff[NB];
  if (tid < NB) { hist[tid] = 0; loff[tid] = 0; }
  __syncthreads();

  int sv[EPT], dv[EPT];
#pragma unroll
  for (int i = 0; i < EPT; ++i) {
    int e = e0 + i * 256 + tid;
    int s = 0, d = -1;
    if (e < TOT_EDGES) {
      if (e < N_EDGES) { s = srcArr[e]; d = dstArr[e]; }
      else { s = e - N_EDGES; d = s; }
    }
    sv[i] = s; dv[i] = d;
    if (d >= 0) atomicAdd(&hist[d >> BSHIFT], 1);
  }
  __syncthreads();
  if (tid < NB) {
    int h = hist[tid];
    if (h > 0) base[tid] = atomicAdd(&bcnt[tid], h);
  }
  __syncthreads();
#pragma unroll
  for (int i = 0; i < EPT; ++i) {
    int d = dv[i];
    if (d >= 0) {
      int b = d >> BSHIFT;
      int p = atomicAdd(&loff[b], 1);
      bbuf[(size_t)b * BCAP + base[b] + p] = ((uint)sv[i] << 9) | (uint)(d & (BNODES - 1));
    }
  }
}

// ---------------- CSR build: phase B (scan of bcnt done per-block) ----------

__global__ __launch_bounds__(512) void partB_kernel(const uint* __restrict__ bbuf,
                                                    const int* __restrict__ bcnt,
                                                    int* __restrict__ rowptr,
                                                    uint* __restrict__ col) {
  int b = blockIdx.x, tid = threadIdx.x;

  __shared__ int s[128];
  if (tid < 128) s[tid] = (tid < NB) ? bcnt[tid] : 0;
  __syncthreads();
  for (int off = 1; off < 128; off <<= 1) {
    int t = 0;
    if (tid < 128 && tid >= off) t = s[tid - off];
    __syncthreads();
    if (tid < 128) s[tid] += t;
    __syncthreads();
  }
  int cb = (b > 0) ? s[b - 1] : 0;
  int m = bcnt[b];
  if (b == 0 && tid == 0) rowptr[N_NODES] = TOT_EDGES;
  const uint* buf = bbuf + (size_t)b * BCAP;

  __shared__ int cnt[BNODES], scn[BNODES], cur[BNODES];
  cnt[tid] = 0;
  __syncthreads();
  for (int e = tid; e < m; e += 512) {
    atomicAdd(&cnt[buf[e] & (BNODES - 1)], 1);
  }
  __syncthreads();
  int c = cnt[tid];
  scn[tid] = c;
  __syncthreads();
  for (int off = 1; off < BNODES; off <<= 1) {
    int t = (tid >= off) ? scn[tid - off] : 0;
    __syncthreads();
    scn[tid] += t;
    __syncthreads();
  }
  int excl = scn[tid] - c;
  int node = b * BNODES + tid;
  if (node < N_NODES) rowptr[node] = cb + excl;
  cur[tid] = excl;
  __syncthreads();
  for (int e = tid; e < m; e += 512) {
    uint sd = buf[e];
    int p = atomicAdd(&cur[sd & (BNODES - 1)], 1);
    col[cb + p] = (sd >> 9) << 2;  // prescaled uint4 row-base in head slice (src*4)
  }
}

// ---------------- MFMA dual GEMM (f16; xl stored HEAD-MAJOR) -----------------

__global__ __launch_bounds__(256) void gemm_mfma_kernel(
    const uint* __restrict__ xb,     // [N][64] f16 pairs
    const ushort* __restrict__ Wt,   // [2][128][128] f16, n-major (this layer)
    const float* __restrict__ bl, const float* __restrict__ br,
    uint* __restrict__ xlh,          // [4][N][16] u32, head-major
    uint* __restrict__ xr) {         // [N][64] f16 pairs, node-major
  int wave = threadIdx.x >> 6, lane = threadIdx.x & 63;
  int lr = lane & 15, kq = lane >> 4;
  int m0 = blockIdx.x * 64;

  bool isR = (wave >> 1) != 0;
  const ushort* W = Wt + (wave >> 1) * (DIM * DIM);
  const float* bias = isR ? br : bl;
  int n0 = (wave & 1) * 64;
  const ushort* xbp = (const ushort*)xb;

  f16x8 bfrag[4][4];
#pragma unroll
  for (int nt = 0; nt < 4; ++nt)
#pragma unroll
    for (int kt = 0; kt < 4; ++kt)
      bfrag[nt][kt] = *(const f16x8*)(W + (n0 + nt * 16 + lr) * DIM + kt * 32 + kq * 8);

  f32x4 acc[4][4];
#pragma unroll
  for (int mt = 0; mt < 4; ++mt)
#pragma unroll
    for (int nt = 0; nt < 4; ++nt)
      acc[mt][nt] = (f32x4){0.f, 0.f, 0.f, 0.f};

  f16x8 af[4];
  {
    int m = m0 + lr;
    int mc = m < N_NODES ? m : N_NODES - 1;
#pragma unroll
    for (int kt = 0; kt < 4; ++kt)
      af[kt] = *(const f16x8*)(xbp + (size_t)mc * DIM + kt * 32 + kq * 8);
  }
#pragma unroll
  for (int mt = 0; mt < 4; ++mt) {
    f16x8 afn[4];
    if (mt < 3) {
      int m2 = m0 + (mt + 1) * 16 + lr;
      int mc2 = m2 < N_NODES ? m2 : N_NODES - 1;
#pragma unroll
      for (int kt = 0; kt < 4; ++kt)
        afn[kt] = *(const f16x8*)(xbp + (size_t)mc2 * DIM + kt * 32 + kq * 8);
    }
#pragma unroll
    for (int nt = 0; nt < 4; ++nt)
#pragma unroll
      for (int kt = 0; kt < 4; ++kt)
        acc[mt][nt] = __builtin_amdgcn_mfma_f32_16x16x32_f16(bfrag[nt][kt], af[kt],
                                                             acc[mt][nt], 0, 0, 0);
    if (mt < 3) {
      af[0] = afn[0]; af[1] = afn[1]; af[2] = afn[2]; af[3] = afn[3];
    }
  }

#pragma unroll
  for (int mt = 0; mt < 4; ++mt) {
    int m = m0 + mt * 16 + lr;
    if (m < N_NODES) {
#pragma unroll
      for (int nt = 0; nt < 4; ++nt) {
        int n = n0 + nt * 16 + kq * 4;
        float4 bb = *(const float4*)(bias + n);
        uint2 o;
        o.x = pk2u(__builtin_amdgcn_cvt_pkrtz(acc[mt][nt][0] + bb.x, acc[mt][nt][1] + bb.y));
        o.y = pk2u(__builtin_amdgcn_cvt_pkrtz(acc[mt][nt][2] + bb.z, acc[mt][nt][3] + bb.w));
        if (!isR) {
          int head = n >> 5;
          uint base = (uint)head * (N_NODES * 16) + (uint)m * 16 + ((uint)(n & 31) >> 1);
          *(uint2*)(xlh + base) = o;
        } else {
          *(uint2*)(xr + (size_t)m * (DIM / 2) + (n >> 1)) = o;
        }
      }
    }
  }
}

// ---------------- per-head attention pass ----------------
// One wave per (node, head); grid head-major (head = bid / N) so the
// concurrent-block window touches ONE head's 3.2MB slice -> L2-resident.
// Lane = (edge-slot e16 = lane>>2, chan-group j4 = lane&3); 8 ch/lane =
// one uint4 gather; 16 edges per iteration. Logit reduce = quadsum4.
// Invalid-edge gathers masked to row 0 (hot line). Writes acc/den-normalized
// per-head output (f16) to hstage; LN happens in epi_kernel.

__global__ __launch_bounds__(64) void atth_kernel(
    const uint4* __restrict__ xlh,   // [4][N][4] uint4 head-major
    const uint4* __restrict__ xrb,   // [N][16] uint4 node-major
    const int* __restrict__ rowptr, const uint* __restrict__ col,
    const uint4* __restrict__ attc,  // [16] uint4 (this layer)
    uint4* __restrict__ hstage) {    // [N][16] uint4
  int lane = threadIdx.x;
  int j4 = lane & 3, e16 = lane >> 2;
  int bid = blockIdx.x;
  int h = bid / N_NODES;
  int n = bid - h * N_NODES;

  uint4 rq = xrb[(uint)n * 16 + h * 4 + j4];
  uint4 aq = attc[h * 4 + j4];
  h2 r2[4] = {u2h(rq.x), u2h(rq.y), u2h(rq.z), u2h(rq.w)};
  h2 at2[4] = {u2h(aq.x), u2h(aq.y), u2h(aq.z), u2h(aq.w)};
  const h2 c02 = {(_Float16)0.2f, (_Float16)0.2f};
  const uint4* xh = xlh + (size_t)h * (N_NODES * 4);

  h2 accp[4] = {};
  float den = 0.f;

  int js = rowptr[n], je = rowptr[n + 1];

  // 2-deep pipeline over 16-edge chunks
  uint cA = col[(uint)(js + e16)];
  bool vA = (js + e16) < je;
  uint4 gA = xh[(vA ? cA : 0u) + (uint)j4];

  for (int cbase = js; cbase < je; cbase += 16) {
    int nb = cbase + 16;
    uint cB = col[(uint)(nb + e16)];
    bool vB = (nb + e16) < je;
    uint4 gB = xh[(vB ? cB : 0u) + (uint)j4];

    h2 a0 = u2h(gA.x), a1 = u2h(gA.y), a2 = u2h(gA.z), a3 = u2h(gA.w);
    float p = 0.f;
    {
      h2 s0 = a0 + r2[0], s1 = a1 + r2[1], s2 = a2 + r2[2], s3 = a3 + r2[3];
      h2 m0 = __builtin_elementwise_max(s0, s0 * c02);
      h2 m1 = __builtin_elementwise_max(s1, s1 * c02);
      h2 m2 = __builtin_elementwise_max(s2, s2 * c02);
      h2 m3 = __builtin_elementwise_max(s3, s3 * c02);
      p = __builtin_amdgcn_fdot2(__builtin_bit_cast(fp16v2, m0),
                                 __builtin_bit_cast(fp16v2, at2[0]), p, false);
      p = __builtin_amdgcn_fdot2(__builtin_bit_cast(fp16v2, m1),
                                 __builtin_bit_cast(fp16v2, at2[1]), p, false);
      p = __builtin_amdgcn_fdot2(__builtin_bit_cast(fp16v2, m2),
                                 __builtin_bit_cast(fp16v2, at2[2]), p, false);
      p = __builtin_amdgcn_fdot2(__builtin_bit_cast(fp16v2, m3),
                                 __builtin_bit_cast(fp16v2, at2[3]), p, false);
    }
    p = quadsum4(p);  // sum over the 4 chan-groups of this edge's head
    float w = vA ? __builtin_amdgcn_exp2f(p) : 0.f;
    den += w;
    _Float16 wh = (_Float16)w;
    h2 w2 = {wh, wh};
    accp[0] = w2 * a0 + accp[0];
    accp[1] = w2 * a1 + accp[1];
    accp[2] = w2 * a2 + accp[2];
    accp[3] = w2 * a3 + accp[3];

    gA = gB; vA = vB;
  }

  // reduce across the 16 edge-slots (lane bits 2..5); j4 (bits 0..1) untouched
#pragma unroll
  for (int t = 0; t < 4; ++t) {
    accp[t] += u2h((uint)__shfl_xor((int)h2u(accp[t]), 4, 64));
    accp[t] += u2h((uint)__shfl_xor((int)h2u(accp[t]), 8, 64));
    accp[t] += u2h((uint)__shfl_xor((int)h2u(accp[t]), 16, 64));
    accp[t] += u2h((uint)__shfl_xor((int)h2u(accp[t]), 32, 64));
  }
  den += __shfl_xor(den, 4, 64);
  den += __shfl_xor(den, 8, 64);
  den += __shfl_xor(den, 16, 64);
  den += __shfl_xor(den, 32, 64);

  if (e16 == 0) {
    float inv = 1.0f / den;
    uint4 ov;
    ov.x = pk2u(__builtin_amdgcn_cvt_pkrtz((float)accp[0].x * inv, (float)accp[0].y * inv));
    ov.y = pk2u(__builtin_amdgcn_cvt_pkrtz((float)accp[1].x * inv, (float)accp[1].y * inv));
    ov.z = pk2u(__builtin_amdgcn_cvt_pkrtz((float)accp[2].x * inv, (float)accp[2].y * inv));
    ov.w = pk2u(__builtin_amdgcn_cvt_pkrtz((float)accp[3].x * inv, (float)accp[3].y * inv));
    hstage[(uint)n * 16 + h * 4 + j4] = ov;
  }
}

// ---------------- epilogue: bias + residual + LayerNorm (+ReLU) -------------
// One wave per node (4 waves/block); lane owns 2 channels.

__global__ __launch_bounds__(256) void epi_kernel(
    const uint* __restrict__ hstage, const uint* __restrict__ xinb,
    const float2* __restrict__ bias, const float2* __restrict__ gamma,
    const float2* __restrict__ beta, uint* __restrict__ xoutb,
    float2* __restrict__ xoutf, int do_relu) {
  int lane = threadIdx.x & 63;
  int n = blockIdx.x * 4 + (threadIdx.x >> 6);
  size_t rowp = (size_t)n * 64 + lane;

  h2 hv = u2h(hstage[rowp]);
  h2 xi = u2h(xinb[rowp]);
  float2 bi = bias[lane];
  float o0 = (float)hv.x + bi.x + (float)xi.x;
  float o1 = (float)hv.y + bi.y + (float)xi.y;

  float s1 = o0 + o1, s2 = o0 * o0 + o1 * o1;
  s1 = rowsum16(s1);
  s2 = rowsum16(s2);
  s1 += __shfl_xor(s1, 16, 64);
  s2 += __shfl_xor(s2, 16, 64);
  s1 += __shfl_xor(s1, 32, 64);
  s2 += __shfl_xor(s2, 32, 64);
  float mean = s1 * (1.0f / DIM);
  float var = s2 * (1.0f / DIM) - mean * mean;
  float rstd = rsqrtf(var + 1e-5f);

  float2 gm = gamma[lane];
  float2 bt = beta[lane];
  float y0 = (o0 - mean) * rstd * gm.x + bt.x;
  float y1 = (o1 - mean) * rstd * gm.y + bt.y;
  if (do_relu) { y0 = fmaxf(y0, 0.f); y1 = fmaxf(y1, 0.f); }
  if (xoutb) xoutb[rowp] = pk2u(__builtin_amdgcn_cvt_pkrtz(y0, y1));
  if (xoutf) xoutf[rowp] = make_float2(y0, y1);
}

// ---------------- launch ----------------

extern "C" void kernel_launch(void* const* d_in, const int* in_sizes, int n_in,
                              void* d_out, int out_size, void* d_ws, size_t ws_size,
                              hipStream_t stream) {
  const float* x_in  = (const float*)d_in[0];
  const int*   eidx  = (const int*)d_in[1];
  const float* Wl    = (const float*)d_in[2];
  const float* bl    = (const float*)d_in[3];
  const float* Wr    = (const float*)d_in[4];
  const float* br    = (const float*)d_in[5];
  const float* att   = (const float*)d_in[6];
  const float* bias  = (const float*)d_in[7];
  const float* gamma = (const float*)d_in[8];
  const float* beta  = (const float*)d_in[9];
  float* out = (float*)d_out;

  char* p = (char*)d_ws;
  auto alloc = [&](size_t bytes) {
    char* q = p;
    p += (bytes + 255) & ~(size_t)255;
    return q;
  };
  uint*  xb       = (uint*)alloc((size_t)N_NODES * 64 * 4);
  uint*  xlh      = (uint*)alloc((size_t)4 * N_NODES * 16 * 4);  // head-major f16
  uint*  xrb      = (uint*)alloc((size_t)N_NODES * 64 * 4);
  uint*  hstage   = (uint*)alloc((size_t)N_NODES * 64 * 4);
  ushort* Wt      = (ushort*)alloc((size_t)3 * 2 * DIM * DIM * 2);
  uint*  attc     = (uint*)alloc((size_t)3 * 64 * 4);
  int*   rowptr   = (int*)alloc((size_t)(N_NODES + 1) * 4);
  uint*  col      = (uint*)alloc((size_t)(TOT_EDGES + 64) * 4);
  uint*  bbuf     = (uint*)alloc((size_t)NB * BCAP * 4);
  int*   bcnt     = (int*)alloc((size_t)NB * 4);

  // prep: 3 dispatches
  conv_kernel<<<CONVX_BLOCKS + CONVW_BLOCKS, 256, 0, stream>>>(
      x_in, xb, bcnt, Wl, Wr, Wt, att, attc, col);
  partA_kernel<<<NBLK_A, 256, 0, stream>>>(eidx, eidx + N_EDGES, bcnt, bbuf);
  partB_kernel<<<NB, 512, 0, stream>>>(bbuf, bcnt, rowptr, col);

  for (int l = 0; l < 3; ++l) {
    gemm_mfma_kernel<<<(N_NODES + 63) / 64, 256, 0, stream>>>(
        xb, Wt + (size_t)l * 2 * DIM * DIM, bl + l * DIM, br + l * DIM, xlh, xrb);
    atth_kernel<<<4 * N_NODES, 64, 0, stream>>>(
        (const uint4*)xlh, (const uint4*)xrb, rowptr, col,
        (const uint4*)(attc + l * 64), (uint4*)hstage);
    epi_kernel<<<(N_NODES + 3) / 4, 256, 0, stream>>>(
        hstage, xb, (const float2*)(bias + l * DIM),
        (const float2*)(gamma + l * DIM), (const float2*)(beta + l * DIM),
        (l == 2) ? nullptr : xb, (l == 2) ? (float2*)out : nullptr,
        (l != 2) ? 1 : 0);
  }
}